// Round 12
// baseline (444.286 us; speedup 1.0000x reference)
//
#include <hip/hip_runtime.h>
#include <hip/hip_bf16.h>
#include <stdint.h>

#define BB 4
#define NN 2048
#define QD 1024
#define NH 16
#define DH 64
#define MTOK (BB*NN)   // 8192
#define SQK 3072       // fused QKV row stride

typedef unsigned short u16;
typedef unsigned long long u64;
typedef __bf16 bf16x8 __attribute__((ext_vector_type(8)));
typedef float  f32x4  __attribute__((ext_vector_type(4)));
typedef uint32_t u32x4 __attribute__((ext_vector_type(4)));

__device__ __forceinline__ u16 f2bf(float f) {
  union { float f; uint32_t u; } v; v.f = f;
  uint32_t u = v.u;
  u += 0x7FFFu + ((u >> 16) & 1u);   // RNE
  return (u16)(u >> 16);
}

__device__ __forceinline__ f32x4 mfma16(bf16x8 a, bf16x8 b, f32x4 c) {
  return __builtin_amdgcn_mfma_f32_16x16x32_bf16(a, b, c, 0, 0, 0);
}

// -------- fused prep: cast + 4x weight transpose + mask expand, one launch ----
// blocks [0,8192): x f32->bf16 cast; [8192,9216): wtrans4; [9216,13312): mask.
//
// MASK LAYOUT (expanded AND-masks for register-P softpack): one u32 per bf16
// PAIR of a lane's packed P word.  u32 index =
//   (((b*16+qt)*4+wave)*2+g)*16384 + kt*512 + lane*8 + ks*4 + p
// value = (mask[q][tok(2p)]>0 ? 0xFFFF:0) | (mask[q][tok(2p+1)]>0 ? 0xFFFF0000:0)
// where q = qt*128+wave*32+g*16+(lane&15), tok(j) = kt*64 + ks*32 + quad*8 + j,
// quad = lane>>4.  attn then masks each packed word with ONE v_and.
__global__ void prep_k(
    const float* __restrict__ x, u16* __restrict__ Xb,
    const float* __restrict__ W0, const float* __restrict__ W1,
    const float* __restrict__ W2, const float* __restrict__ W3,
    u16* __restrict__ D0, u16* __restrict__ D1,
    u16* __restrict__ D2, u16* __restrict__ D3,
    const int* __restrict__ mk, uint32_t* __restrict__ Mx32) {
  __shared__ float t[64][65];
  const int bid = blockIdx.x, tid = threadIdx.x;
  if (bid < 8192) {
    int i = (bid * 256 + tid) * 4;
    float4 v = *(const float4*)(x + i);
    ushort4 o;
    o.x = f2bf(v.x); o.y = f2bf(v.y); o.z = f2bf(v.z); o.w = f2bf(v.w);
    *(ushort4*)(Xb + i) = o;
  } else if (bid < 9216) {
    int wb = bid - 8192;
    int sel = wb >> 8, b2 = wb & 255;
    const float* W = sel == 0 ? W0 : sel == 1 ? W1 : sel == 2 ? W2 : W3;
    u16* Wt = sel == 0 ? D0 : sel == 1 ? D1 : sel == 2 ? D2 : D3;
    int n0 = (b2 & 15) * 64, k0 = (b2 >> 4) * 64;
    int c = tid & 63, r0 = tid >> 6;
    for (int r = r0; r < 64; r += 4)
      t[r][c] = W[(size_t)(k0 + r) * QD + n0 + c];
    __syncthreads();
    for (int n = r0; n < 64; n += 4)
      Wt[(size_t)(n0 + n) * QD + k0 + c] = f2bf(t[c][n]);
  } else {
    // one thread = one lane's 8 words (32B) for one (b,qt,wave,g,kt)
    int widx = (bid - 9216) * 256 + tid;          // 2^20 threads
    int lane = widx & 63;
    int kt   = (widx >> 6) & 31;
    int g    = (widx >> 11) & 1;
    int wave = (widx >> 12) & 3;
    int qt   = (widx >> 14) & 15;
    int b    = widx >> 18;
    int l15 = lane & 15, quad = lane >> 4;
    int q = qt * 128 + wave * 32 + g * 16 + l15;
    size_t base = (size_t)(b * NN + q) * NN + kt * 64 + quad * 8;
    int4 v0 = *(const int4*)(mk + base);          // ks=0, j=0..3
    int4 v1 = *(const int4*)(mk + base + 4);      // ks=0, j=4..7
    int4 v2 = *(const int4*)(mk + base + 32);     // ks=1, j=0..3
    int4 v3 = *(const int4*)(mk + base + 36);     // ks=1, j=4..7
    u32x4 w0, w1;
    w0[0] = (v0.x > 0 ? 0xFFFFu : 0u) | (v0.y > 0 ? 0xFFFF0000u : 0u);
    w0[1] = (v0.z > 0 ? 0xFFFFu : 0u) | (v0.w > 0 ? 0xFFFF0000u : 0u);
    w0[2] = (v1.x > 0 ? 0xFFFFu : 0u) | (v1.y > 0 ? 0xFFFF0000u : 0u);
    w0[3] = (v1.z > 0 ? 0xFFFFu : 0u) | (v1.w > 0 ? 0xFFFF0000u : 0u);
    w1[0] = (v2.x > 0 ? 0xFFFFu : 0u) | (v2.y > 0 ? 0xFFFF0000u : 0u);
    w1[1] = (v2.z > 0 ? 0xFFFFu : 0u) | (v2.w > 0 ? 0xFFFF0000u : 0u);
    w1[2] = (v3.x > 0 ? 0xFFFFu : 0u) | (v3.y > 0 ? 0xFFFF0000u : 0u);
    w1[3] = (v3.z > 0 ? 0xFFFFu : 0u) | (v3.w > 0 ? 0xFFFF0000u : 0u);
    uint32_t* dst = Mx32 + (size_t)widx * 8;
    *(u32x4*)(dst) = w0;
    *(u32x4*)(dst + 4) = w1;
  }
}

// -------- V slice of QKV [8192][3072] -> Vt[b][h][d][tok] bf16 --------
__global__ void vtrans_k(const u16* __restrict__ V, u16* __restrict__ Vt) {
  __shared__ u16 t[64][65];
  int bid = blockIdx.x;
  int tt = bid & 31, h = (bid >> 5) & 15, b = bid >> 9;
  int c = threadIdx.x & 63, r0 = threadIdx.x >> 6;
  for (int r = r0; r < 64; r += 4)
    t[r][c] = V[(size_t)(b * NN + tt * 64 + r) * SQK + h * DH + c];
  __syncthreads();
  for (int d = r0; d < 64; d += 4)
    Vt[(size_t)((b * NH + h) * DH + d) * NN + tt * 64 + c] = t[c][d];
}

// -------- GEMM C[M,N] = A[M,K] @ Bt[N,K]^T ; 128x128x64 tiles, 4 waves --------
// Register-prefetch pipeline; plain blockIdx mapping (R3's proven form —
// R7's XCD swizzle measured +6.7us and was reverted).
template<int OUTMODE>
__global__ __launch_bounds__(256, 3) void gemm_bt_k(
    const u16* __restrict__ A, const u16* __restrict__ Bt,
    void* __restrict__ Cv, const float* __restrict__ bias,
    float scale, int scaleN, int M, int Nn, int Kd) {
  __shared__ __align__(16) u16 As[128 * 64];
  __shared__ __align__(16) u16 Bs[128 * 64];
  const int tid = threadIdx.x;
  const int lane = tid & 63, wave = tid >> 6;
  const int wm = wave >> 1, wn = wave & 1;
  const int l15 = lane & 15, quad = lane >> 4;
  const int bm = blockIdx.y, bn = blockIdx.x;

  f32x4 acc[4][4];
#pragma unroll
  for (int i = 0; i < 4; i++)
#pragma unroll
    for (int j = 0; j < 4; j++) acc[i][j] = (f32x4){0.f, 0.f, 0.f, 0.f};

  const u16* Ab = A + (size_t)(bm * 128) * Kd;
  const u16* Bb = Bt + (size_t)(bn * 128) * Kd;

  int sofs[4];
#pragma unroll
  for (int p = 0; p < 4; p++) {
    int s = p * 2048 + tid * 8;
    int row = s >> 6, cp = (s >> 3) & 7;
    sofs[p] = row * Kd + ((cp ^ (row & 7)) * 8);
  }

  int fA[2][4], fB[2][4];
#pragma unroll
  for (int ks = 0; ks < 2; ks++) {
#pragma unroll
    for (int mt = 0; mt < 4; mt++) {
      int row = wm * 64 + mt * 16 + l15;
      fA[ks][mt] = row * 64 + (((ks * 4 + quad) ^ (row & 7)) * 8);
    }
#pragma unroll
    for (int nt = 0; nt < 4; nt++) {
      int row = wn * 64 + nt * 16 + l15;
      fB[ks][nt] = row * 64 + (((ks * 4 + quad) ^ (row & 7)) * 8);
    }
  }

  u32x4 pa[4], pb[4];
#pragma unroll
  for (int p = 0; p < 4; p++) {
    pa[p] = *(const u32x4*)(Ab + sofs[p]);
    pb[p] = *(const u32x4*)(Bb + sofs[p]);
  }

  for (int k0 = 0; k0 < Kd; k0 += 64) {
    __syncthreads();
#pragma unroll
    for (int p = 0; p < 4; p++) {
      int s = p * 2048 + tid * 8;
      *(u32x4*)(As + s) = pa[p];
      *(u32x4*)(Bs + s) = pb[p];
    }
    const int kn = (k0 + 64 < Kd) ? k0 + 64 : 0;
#pragma unroll
    for (int p = 0; p < 4; p++) {
      pa[p] = *(const u32x4*)(Ab + kn + sofs[p]);
      pb[p] = *(const u32x4*)(Bb + kn + sofs[p]);
    }
    __syncthreads();
#pragma unroll
    for (int ks = 0; ks < 2; ks++) {
      bf16x8 af[4], bf[4];
#pragma unroll
      for (int mt = 0; mt < 4; mt++) af[mt] = *(const bf16x8*)(As + fA[ks][mt]);
#pragma unroll
      for (int nt = 0; nt < 4; nt++) bf[nt] = *(const bf16x8*)(Bs + fB[ks][nt]);
#pragma unroll
      for (int mt = 0; mt < 4; mt++)
#pragma unroll
        for (int nt = 0; nt < 4; nt++)
          acc[mt][nt] = mfma16(af[mt], bf[nt], acc[mt][nt]);
    }
  }

  const int row0 = bm * 128 + wm * 64;
  const int col0 = bn * 128 + wn * 64;
  if (OUTMODE == 0) {
    const float sc = (bn * 128 < scaleN) ? scale : 1.0f;
    u16* C = (u16*)Cv;
#pragma unroll
    for (int mt = 0; mt < 4; mt++)
#pragma unroll
      for (int nt = 0; nt < 4; nt++)
#pragma unroll
        for (int r = 0; r < 4; r++) {
          int row = row0 + mt * 16 + quad * 4 + r;
          int col = col0 + nt * 16 + l15;
          C[(size_t)row * Nn + col] = f2bf(acc[mt][nt][r] * sc);
        }
  } else {
    float* C = (float*)Cv;
#pragma unroll
    for (int mt = 0; mt < 4; mt++)
#pragma unroll
      for (int nt = 0; nt < 4; nt++)
#pragma unroll
        for (int r = 0; r < 4; r++) {
          int row = row0 + mt * 16 + quad * 4 + r;
          int col = col0 + nt * 16 + l15;
          C[(size_t)row * Nn + col] = acc[mt][nt][r] + bias[col];
        }
  }
}

// -------- flash attention: swapped QK^T, register-resident P, lean softpack --------
// R11 green base (89.8us attn, 323.3us total — session best) + SINGLE DELTA:
// launch_bounds (256,3) -> (256,4).  Occupancy anomaly: ~25% (2 blocks/CU)
// in EVERY config (R3/R10/R11 at 32KB LDS, R4/R9 at 16KB) though resource
// math allows 4 blocks (128KB LDS, 4 waves/SIMD x 80 VGPR).  Suspect: the
// waves-per-eu metadata from the 2nd launch_bounds arg caps residency.
// (256,4) caps VGPR at 128 >> measured 80, so no spill pressure; dataflow
// untouched (the two proven miscompile triggers — exp2-fold on this
// structure, loads-before-stage-writes — are absent).  If occupancy rises,
// the DS/VALU lockstep remainder compresses; if null, residency limiter is
// beyond source control and R11 is the session optimum.
// VGPR expect ~80-84.  LDS 32KB.
__global__ __launch_bounds__(256, 4) void attn_k(
    const u16* __restrict__ Q, const u16* __restrict__ K,
    const u16* __restrict__ Vt, const uint32_t* __restrict__ Mx32,
    u16* __restrict__ O) {
  __shared__ __align__(16) u16 Ks[2 * 64 * 64];
  __shared__ __align__(16) u16 Vs[2 * 64 * 64];   // [d][tok] within tile

  const int bid = blockIdx.x;
  const int qt = bid & 15;          // 128-row q tile
  const int h  = (bid >> 4) & 15;
  const int b  = bid >> 8;
  const int tid = threadIdx.x;
  const int lane = tid & 63, wave = tid >> 6;
  const int l15 = lane & 15, quad = lane >> 4;

  // Q fragments (B-operand of swapped QK^T): rows qt*128 + wave*32 + g*16 + l15
  const u16* Qr0 = Q + (size_t)(b * NN + qt * 128 + wave * 32 + l15) * SQK + h * DH;
  const u16* Qr1 = Qr0 + (size_t)16 * SQK;
  const bf16x8 aq00 = *(const bf16x8*)(Qr0 + quad * 8);
  const bf16x8 aq01 = *(const bf16x8*)(Qr0 + 32 + quad * 8);
  const bf16x8 aq10 = *(const bf16x8*)(Qr1 + quad * 8);
  const bf16x8 aq11 = *(const bf16x8*)(Qr1 + 32 + quad * 8);

  // staging: LDS slot i -> (row r, physical chunk c); source chunk c^(r&7)
  // (XOR swizzle folded into the GLOBAL gather, LDS writes lane-linear).
  // K rows sigma-permuted: LDS key-row j holds token sigma(j) =
  // bit-permute [b5][b4][b3b2][b1b0] -> [b5][b3b2][b4][b1b0].
  const int i0 = tid, i1 = tid + 256;
  const int r0 = i0 >> 3, s0c = (i0 & 7) ^ (r0 & 7);
  const int r1 = i1 >> 3, s1c = (i1 & 7) ^ (r1 & 7);
  const int kr0 = (r0 & 35) | ((r0 & 12) << 1) | ((r0 & 16) >> 2);  // sigma(r0)
  const int kr1 = (r1 & 35) | ((r1 & 12) << 1) | ((r1 & 16) >> 2);  // sigma(r1)
  const u16* Kp0 = K + (size_t)(b * NN + kr0) * SQK + h * DH + s0c * 8;
  const u16* Kp1 = K + (size_t)(b * NN + kr1) * SQK + h * DH + s1c * 8;
  const u16* Vp0 = Vt + (size_t)((b * NH + h) * DH + r0) * NN + s0c * 8;
  const u16* Vp1 = Vt + (size_t)((b * NH + h) * DH + r1) * NN + s1c * 8;
  const uint32_t* Mp = Mx32 +
      (size_t)(((b * 16 + qt) * 4 + wave) * 2) * 16384 + lane * 8;

  // prologue: tile 0 -> buf0; prefetch tile 1 to regs
  u32x4 krg0 = *(const u32x4*)Kp0;
  u32x4 krg1 = *(const u32x4*)Kp1;
  u32x4 vrg0 = *(const u32x4*)Vp0;
  u32x4 vrg1 = *(const u32x4*)Vp1;
  *(u32x4*)(Ks + i0 * 8) = krg0;
  *(u32x4*)(Ks + i1 * 8) = krg1;
  *(u32x4*)(Vs + i0 * 8) = vrg0;
  *(u32x4*)(Vs + i1 * 8) = vrg1;
  krg0 = *(const u32x4*)(Kp0 + (size_t)64 * SQK);
  krg1 = *(const u32x4*)(Kp1 + (size_t)64 * SQK);
  vrg0 = *(const u32x4*)(Vp0 + 64);
  vrg1 = *(const u32x4*)(Vp1 + 64);

  f32x4 oacc0[4], oacc1[4];
#pragma unroll
  for (int d = 0; d < 4; d++) {
    oacc0[d] = (f32x4){0.f, 0.f, 0.f, 0.f};
    oacc1[d] = (f32x4){0.f, 0.f, 0.f, 0.f};
  }
  f32x4 ol0 = (f32x4){0.f, 0.f, 0.f, 0.f};
  f32x4 ol1 = (f32x4){0.f, 0.f, 0.f, 0.f};

  bf16x8 ones;
  {
    union { uint32_t u; __bf16 h2[2]; } c; c.u = 0x3F803F80u;  // 1.0bf16 x2
#pragma unroll
    for (int j = 0; j < 8; j++) ones[j] = c.h2[0];
  }

  __syncthreads();                         // buf0 visible

  // p = exp(s-20) = exp2(fma(s,log2e,-20*log2e)); cvt_pk packs the pair;
  // one v_and applies both 16-bit masks.
#define SOFTPACK(SARR, M0, M1, APU)                                           \
  do {                                                                        \
    _Pragma("unroll")                                                         \
    for (int ks = 0; ks < 2; ks++) {                                          \
      _Pragma("unroll")                                                       \
      for (int p = 0; p < 4; p++) {                                           \
        int nt = ks * 2 + (p >> 1);                                           \
        int rr = (p & 1) * 2;                                                 \
        float p0 = __builtin_amdgcn_exp2f(__builtin_fmaf(                     \
            SARR[nt][rr], 1.4426950408889634f, -28.853900817779268f));        \
        float p1 = __builtin_amdgcn_exp2f(__builtin_fmaf(                     \
            SARR[nt][rr + 1], 1.4426950408889634f, -28.853900817779268f));    \
        uint32_t word;                                                        \
        asm("v_cvt_pk_bf16_f32 %0, %1, %2" : "=v"(word) : "v"(p0), "v"(p1));  \
        word &= (ks == 0 ? M0 : M1)[p];                                       \
        APU[ks].u[p] = word;                                                  \
      }                                                                       \
    }                                                                         \
  } while (0)

  for (int kt = 0; kt < 32; kt++) {
    // write tile kt+1 -> buf[(kt+1)&1] (vmcnt wait: loads issued one full
    // compute phase ago); then prefetch tile kt+2
    const int wb = ((kt + 1) & 1) * 4096;
    *(u32x4*)(Ks + wb + i0 * 8) = krg0;
    *(u32x4*)(Ks + wb + i1 * 8) = krg1;
    *(u32x4*)(Vs + wb + i0 * 8) = vrg0;
    *(u32x4*)(Vs + wb + i1 * 8) = vrg1;
    krg0 = *(const u32x4*)(Kp0 + (size_t)(kt + 2) * 64 * SQK);
    krg1 = *(const u32x4*)(Kp1 + (size_t)(kt + 2) * 64 * SQK);
    vrg0 = *(const u32x4*)(Vp0 + (kt + 2) * 64);
    vrg1 = *(const u32x4*)(Vp1 + (kt + 2) * 64);
    // mask loads for CURRENT tile (L3-resident; consumed after S phase)
    const uint32_t* Mpk = Mp + kt * 512;
    const u32x4 m0a = *(const u32x4*)(Mpk);
    const u32x4 m0b = *(const u32x4*)(Mpk + 4);
    const u32x4 m1a = *(const u32x4*)(Mpk + 16384);
    const u32x4 m1b = *(const u32x4*)(Mpk + 16384 + 4);

    const u16* Kb = Ks + (kt & 1) * 4096;
    const u16* Vb = Vs + (kt & 1) * 4096;

    // S^T tiles: s = mfma(K_frag, Q_frag); each bk read feeds both g-groups.
    f32x4 s0[4], s1[4];
#pragma unroll
    for (int nt = 0; nt < 4; nt++) {
      s0[nt] = (f32x4){0.f, 0.f, 0.f, 0.f};
      s1[nt] = (f32x4){0.f, 0.f, 0.f, 0.f};
    }
    __builtin_amdgcn_s_setprio(1);         // T5: favor MFMA-issuing wave
#pragma unroll
    for (int nt = 0; nt < 4; nt++) {
      int krow = nt * 16 + l15;
      bf16x8 bkl = *(const bf16x8*)(Kb + krow * 64 + ((quad ^ (krow & 7)) * 8));
      s0[nt] = mfma16(bkl, aq00, s0[nt]);
      s1[nt] = mfma16(bkl, aq10, s1[nt]);
    }
#pragma unroll
    for (int nt = 0; nt < 4; nt++) {
      int krow = nt * 16 + l15;
      bf16x8 bkh = *(const bf16x8*)(Kb + krow * 64 + (((4 + quad) ^ (krow & 7)) * 8));
      s0[nt] = mfma16(bkh, aq01, s0[nt]);
      s1[nt] = mfma16(bkh, aq11, s1[nt]);
    }
    __builtin_amdgcn_s_setprio(0);

    // softmax + bf16 pack + mask, all in registers
    union U { uint32_t u[4]; bf16x8 v; };
    U ap0[2], ap1[2];
    SOFTPACK(s0, m0a, m0b, ap0);
    SOFTPACK(s1, m1a, m1b, ap1);

    // O += P @ V ; l += P @ 1 ; each bv read feeds both g-groups
    __builtin_amdgcn_s_setprio(1);         // T5
#pragma unroll
    for (int ks = 0; ks < 2; ks++) {
      ol0 = mfma16(ap0[ks].v, ones, ol0);
      ol1 = mfma16(ap1[ks].v, ones, ol1);
#pragma unroll
      for (int d = 0; d < 4; d++) {
        int vrow = d * 16 + l15;
        bf16x8 bv = *(const bf16x8*)(Vb + vrow * 64 + (((ks * 4 + quad) ^ (vrow & 7)) * 8));
        oacc0[d] = mfma16(ap0[ks].v, bv, oacc0[d]);
        oacc1[d] = mfma16(ap1[ks].v, bv, oacc1[d]);
      }
    }
    __builtin_amdgcn_s_setprio(0);
    __syncthreads();   // all waves wrote buf[(kt+1)&1] and finished buf[kt&1]
  }
#undef SOFTPACK

  // D rows = quad*4+r within each 16-row group; g=1 is +16 rows
  u16* Og = O + (size_t)(b * NN + qt * 128 + wave * 32 + quad * 4) * QD + h * DH;
#pragma unroll
  for (int r = 0; r < 4; r++) {
    float inv0 = 1.0f / ol0[r];
    float inv1 = 1.0f / ol1[r];
#pragma unroll
    for (int d = 0; d < 4; d++) {
      Og[(size_t)r * QD + d * 16 + l15] = f2bf(oacc0[d][r] * inv0);
      Og[(size_t)(16 + r) * QD + d * 16 + l15] = f2bf(oacc1[d][r] * inv1);
    }
  }
}

extern "C" void kernel_launch(void* const* d_in, const int* in_sizes, int n_in,
                              void* d_out, int out_size, void* d_ws, size_t ws_size,
                              hipStream_t stream) {
  const float* x  = (const float*)d_in[0];
  const int*   mk = (const int*)d_in[1];
  const float* Wq = (const float*)d_in[2];
  const float* Wk = (const float*)d_in[3];
  const float* Wv = (const float*)d_in[4];
  const float* Wo = (const float*)d_in[5];
  const float* bo = (const float*)d_in[6];
  float* out = (float*)d_out;

  char* ws = (char*)d_ws;
  u16* Xb   = (u16*)(ws);                                  // 16 MB
  u16* QKVb = (u16*)(ws + 16777216);                       // 48 MB [8192][3072]
  u16* Vt   = (u16*)(ws + 16777216 + 50331648);            // 16 MB
  u16* Ob   = Xb;  // alias: Xb dead after gemm1; attn writes Ob after gemm1
  char* wx  =  ws + 16777216 + 50331648 + 16777216;        // @80 MB
  u16* Wqkvt = (u16*)(wx);                                 // 6 MB [3072][1024]
  u16* Wot   = (u16*)(wx + 6291456);                       // 2 MB
  uint32_t* Mx32 = (uint32_t*)(wx + 6291456 + 2097152);    // 32 MB @88 MB
  // total ws use: 16+48+16+6+2+32 = 120 MB

  prep_k<<<13312, 256, 0, stream>>>(x, Xb, Wq, Wk, Wv, Wo,
      Wqkvt, Wqkvt + 1024 * QD, Wqkvt + 2048 * QD, Wot, mk, Mx32);

  // fused QKV projection: [8192][1024] x [1024][3072] -> [8192][3072], Q cols scaled 1/8
  gemm_bt_k<0><<<dim3(SQK / 128, MTOK / 128), 256, 0, stream>>>(
      Xb, Wqkvt, QKVb, nullptr, 0.125f, 1024, MTOK, SQK, QD);

  vtrans_k<<<BB * NH * (NN / 64), 256, 0, stream>>>(QKVb + 2048, Vt);
  attn_k<<<BB * NH * (NN / 128), 256, 0, stream>>>(QKVb, QKVb + 1024, Vt, Mx32, Ob);

  gemm_bt_k<1><<<dim3(QD / 128, MTOK / 128), 256, 0, stream>>>(
      Ob, Wot, out, bo, 1.0f, 0, MTOK, QD, QD);
}

// Round 13
// 322.708 us; speedup vs baseline: 1.3767x; 1.3767x over previous
//
#include <hip/hip_runtime.h>
#include <hip/hip_bf16.h>
#include <stdint.h>

#define BB 4
#define NN 2048
#define QD 1024
#define NH 16
#define DH 64
#define MTOK (BB*NN)   // 8192
#define SQK 3072       // fused QKV row stride

typedef unsigned short u16;
typedef unsigned long long u64;
typedef __bf16 bf16x8 __attribute__((ext_vector_type(8)));
typedef float  f32x4  __attribute__((ext_vector_type(4)));
typedef uint32_t u32x4 __attribute__((ext_vector_type(4)));

__device__ __forceinline__ u16 f2bf(float f) {
  union { float f; uint32_t u; } v; v.f = f;
  uint32_t u = v.u;
  u += 0x7FFFu + ((u >> 16) & 1u);   // RNE
  return (u16)(u >> 16);
}

__device__ __forceinline__ f32x4 mfma16(bf16x8 a, bf16x8 b, f32x4 c) {
  return __builtin_amdgcn_mfma_f32_16x16x32_bf16(a, b, c, 0, 0, 0);
}

// -------- fused prep: cast + 4x weight transpose + mask expand, one launch ----
// blocks [0,8192): x f32->bf16 cast; [8192,9216): wtrans4; [9216,13312): mask.
//
// MASK LAYOUT (expanded AND-masks for register-P softpack): one u32 per bf16
// PAIR of a lane's packed P word.  u32 index =
//   (((b*16+qt)*4+wave)*2+g)*16384 + kt*512 + lane*8 + ks*4 + p
// value = (mask[q][tok(2p)]>0 ? 0xFFFF:0) | (mask[q][tok(2p+1)]>0 ? 0xFFFF0000:0)
// where q = qt*128+wave*32+g*16+(lane&15), tok(j) = kt*64 + ks*32 + quad*8 + j,
// quad = lane>>4.  attn then masks each packed word with ONE v_and.
__global__ void prep_k(
    const float* __restrict__ x, u16* __restrict__ Xb,
    const float* __restrict__ W0, const float* __restrict__ W1,
    const float* __restrict__ W2, const float* __restrict__ W3,
    u16* __restrict__ D0, u16* __restrict__ D1,
    u16* __restrict__ D2, u16* __restrict__ D3,
    const int* __restrict__ mk, uint32_t* __restrict__ Mx32) {
  __shared__ float t[64][65];
  const int bid = blockIdx.x, tid = threadIdx.x;
  if (bid < 8192) {
    int i = (bid * 256 + tid) * 4;
    float4 v = *(const float4*)(x + i);
    ushort4 o;
    o.x = f2bf(v.x); o.y = f2bf(v.y); o.z = f2bf(v.z); o.w = f2bf(v.w);
    *(ushort4*)(Xb + i) = o;
  } else if (bid < 9216) {
    int wb = bid - 8192;
    int sel = wb >> 8, b2 = wb & 255;
    const float* W = sel == 0 ? W0 : sel == 1 ? W1 : sel == 2 ? W2 : W3;
    u16* Wt = sel == 0 ? D0 : sel == 1 ? D1 : sel == 2 ? D2 : D3;
    int n0 = (b2 & 15) * 64, k0 = (b2 >> 4) * 64;
    int c = tid & 63, r0 = tid >> 6;
    for (int r = r0; r < 64; r += 4)
      t[r][c] = W[(size_t)(k0 + r) * QD + n0 + c];
    __syncthreads();
    for (int n = r0; n < 64; n += 4)
      Wt[(size_t)(n0 + n) * QD + k0 + c] = f2bf(t[c][n]);
  } else {
    // one thread = one lane's 8 words (32B) for one (b,qt,wave,g,kt)
    int widx = (bid - 9216) * 256 + tid;          // 2^20 threads
    int lane = widx & 63;
    int kt   = (widx >> 6) & 31;
    int g    = (widx >> 11) & 1;
    int wave = (widx >> 12) & 3;
    int qt   = (widx >> 14) & 15;
    int b    = widx >> 18;
    int l15 = lane & 15, quad = lane >> 4;
    int q = qt * 128 + wave * 32 + g * 16 + l15;
    size_t base = (size_t)(b * NN + q) * NN + kt * 64 + quad * 8;
    int4 v0 = *(const int4*)(mk + base);          // ks=0, j=0..3
    int4 v1 = *(const int4*)(mk + base + 4);      // ks=0, j=4..7
    int4 v2 = *(const int4*)(mk + base + 32);     // ks=1, j=0..3
    int4 v3 = *(const int4*)(mk + base + 36);     // ks=1, j=4..7
    u32x4 w0, w1;
    w0[0] = (v0.x > 0 ? 0xFFFFu : 0u) | (v0.y > 0 ? 0xFFFF0000u : 0u);
    w0[1] = (v0.z > 0 ? 0xFFFFu : 0u) | (v0.w > 0 ? 0xFFFF0000u : 0u);
    w0[2] = (v1.x > 0 ? 0xFFFFu : 0u) | (v1.y > 0 ? 0xFFFF0000u : 0u);
    w0[3] = (v1.z > 0 ? 0xFFFFu : 0u) | (v1.w > 0 ? 0xFFFF0000u : 0u);
    w1[0] = (v2.x > 0 ? 0xFFFFu : 0u) | (v2.y > 0 ? 0xFFFF0000u : 0u);
    w1[1] = (v2.z > 0 ? 0xFFFFu : 0u) | (v2.w > 0 ? 0xFFFF0000u : 0u);
    w1[2] = (v3.x > 0 ? 0xFFFFu : 0u) | (v3.y > 0 ? 0xFFFF0000u : 0u);
    w1[3] = (v3.z > 0 ? 0xFFFFu : 0u) | (v3.w > 0 ? 0xFFFF0000u : 0u);
    uint32_t* dst = Mx32 + (size_t)widx * 8;
    *(u32x4*)(dst) = w0;
    *(u32x4*)(dst + 4) = w1;
  }
}

// -------- V slice of QKV [8192][3072] -> Vt[b][h][d][tok] bf16 --------
__global__ void vtrans_k(const u16* __restrict__ V, u16* __restrict__ Vt) {
  __shared__ u16 t[64][65];
  int bid = blockIdx.x;
  int tt = bid & 31, h = (bid >> 5) & 15, b = bid >> 9;
  int c = threadIdx.x & 63, r0 = threadIdx.x >> 6;
  for (int r = r0; r < 64; r += 4)
    t[r][c] = V[(size_t)(b * NN + tt * 64 + r) * SQK + h * DH + c];
  __syncthreads();
  for (int d = r0; d < 64; d += 4)
    Vt[(size_t)((b * NH + h) * DH + d) * NN + tt * 64 + c] = t[c][d];
}

// -------- GEMM C[M,N] = A[M,K] @ Bt[N,K]^T ; 128x128x64 tiles, 4 waves --------
// Register-prefetch pipeline; plain blockIdx mapping (R3's proven form —
// R7's XCD swizzle measured +6.7us and was reverted).
template<int OUTMODE>
__global__ __launch_bounds__(256, 3) void gemm_bt_k(
    const u16* __restrict__ A, const u16* __restrict__ Bt,
    void* __restrict__ Cv, const float* __restrict__ bias,
    float scale, int scaleN, int M, int Nn, int Kd) {
  __shared__ __align__(16) u16 As[128 * 64];
  __shared__ __align__(16) u16 Bs[128 * 64];
  const int tid = threadIdx.x;
  const int lane = tid & 63, wave = tid >> 6;
  const int wm = wave >> 1, wn = wave & 1;
  const int l15 = lane & 15, quad = lane >> 4;
  const int bm = blockIdx.y, bn = blockIdx.x;

  f32x4 acc[4][4];
#pragma unroll
  for (int i = 0; i < 4; i++)
#pragma unroll
    for (int j = 0; j < 4; j++) acc[i][j] = (f32x4){0.f, 0.f, 0.f, 0.f};

  const u16* Ab = A + (size_t)(bm * 128) * Kd;
  const u16* Bb = Bt + (size_t)(bn * 128) * Kd;

  int sofs[4];
#pragma unroll
  for (int p = 0; p < 4; p++) {
    int s = p * 2048 + tid * 8;
    int row = s >> 6, cp = (s >> 3) & 7;
    sofs[p] = row * Kd + ((cp ^ (row & 7)) * 8);
  }

  int fA[2][4], fB[2][4];
#pragma unroll
  for (int ks = 0; ks < 2; ks++) {
#pragma unroll
    for (int mt = 0; mt < 4; mt++) {
      int row = wm * 64 + mt * 16 + l15;
      fA[ks][mt] = row * 64 + (((ks * 4 + quad) ^ (row & 7)) * 8);
    }
#pragma unroll
    for (int nt = 0; nt < 4; nt++) {
      int row = wn * 64 + nt * 16 + l15;
      fB[ks][nt] = row * 64 + (((ks * 4 + quad) ^ (row & 7)) * 8);
    }
  }

  u32x4 pa[4], pb[4];
#pragma unroll
  for (int p = 0; p < 4; p++) {
    pa[p] = *(const u32x4*)(Ab + sofs[p]);
    pb[p] = *(const u32x4*)(Bb + sofs[p]);
  }

  for (int k0 = 0; k0 < Kd; k0 += 64) {
    __syncthreads();
#pragma unroll
    for (int p = 0; p < 4; p++) {
      int s = p * 2048 + tid * 8;
      *(u32x4*)(As + s) = pa[p];
      *(u32x4*)(Bs + s) = pb[p];
    }
    const int kn = (k0 + 64 < Kd) ? k0 + 64 : 0;
#pragma unroll
    for (int p = 0; p < 4; p++) {
      pa[p] = *(const u32x4*)(Ab + kn + sofs[p]);
      pb[p] = *(const u32x4*)(Bb + kn + sofs[p]);
    }
    __syncthreads();
#pragma unroll
    for (int ks = 0; ks < 2; ks++) {
      bf16x8 af[4], bf[4];
#pragma unroll
      for (int mt = 0; mt < 4; mt++) af[mt] = *(const bf16x8*)(As + fA[ks][mt]);
#pragma unroll
      for (int nt = 0; nt < 4; nt++) bf[nt] = *(const bf16x8*)(Bs + fB[ks][nt]);
#pragma unroll
      for (int mt = 0; mt < 4; mt++)
#pragma unroll
        for (int nt = 0; nt < 4; nt++)
          acc[mt][nt] = mfma16(af[mt], bf[nt], acc[mt][nt]);
    }
  }

  const int row0 = bm * 128 + wm * 64;
  const int col0 = bn * 128 + wn * 64;
  if (OUTMODE == 0) {
    const float sc = (bn * 128 < scaleN) ? scale : 1.0f;
    u16* C = (u16*)Cv;
#pragma unroll
    for (int mt = 0; mt < 4; mt++)
#pragma unroll
      for (int nt = 0; nt < 4; nt++)
#pragma unroll
        for (int r = 0; r < 4; r++) {
          int row = row0 + mt * 16 + quad * 4 + r;
          int col = col0 + nt * 16 + l15;
          C[(size_t)row * Nn + col] = f2bf(acc[mt][nt][r] * sc);
        }
  } else {
    float* C = (float*)Cv;
#pragma unroll
    for (int mt = 0; mt < 4; mt++)
#pragma unroll
      for (int nt = 0; nt < 4; nt++)
#pragma unroll
        for (int r = 0; r < 4; r++) {
          int row = row0 + mt * 16 + quad * 4 + r;
          int col = col0 + nt * 16 + l15;
          C[(size_t)row * Nn + col] = acc[mt][nt][r] + bias[col];
        }
  }
}

// -------- flash attention: swapped QK^T, register-resident P, lean softpack --------
// BYTE-EXACT R11 (session best: 89.8us attn, 323.3us total, PASS).
// R12 post-mortem closed the occupancy question: launch_bounds (256,4)
// forced VGPR 80->64, kernel spilled to scratch (WRITE_SIZE 16->294 MB,
// FETCH 164->473 MB), attn 90->207us despite occupancy 25->40%.  At 256
// threads the waves-per-EU quantization offers only 64- or 128-VGPR
// operating points; this kernel needs ~80 -> (256,3) / 2 blocks/CU is the
// feasible optimum.  Full session ledger in prior round comments:
// V-direct latency-bound (~165us) without asm vmcnt; exp2-fold and
// load-reorders miscompile on this structure; GEMM XCD swizzle +6.7us.
// launch_bounds(256,3): VGPR 80 measured.  LDS 32KB.
__global__ __launch_bounds__(256, 3) void attn_k(
    const u16* __restrict__ Q, const u16* __restrict__ K,
    const u16* __restrict__ Vt, const uint32_t* __restrict__ Mx32,
    u16* __restrict__ O) {
  __shared__ __align__(16) u16 Ks[2 * 64 * 64];
  __shared__ __align__(16) u16 Vs[2 * 64 * 64];   // [d][tok] within tile

  const int bid = blockIdx.x;
  const int qt = bid & 15;          // 128-row q tile
  const int h  = (bid >> 4) & 15;
  const int b  = bid >> 8;
  const int tid = threadIdx.x;
  const int lane = tid & 63, wave = tid >> 6;
  const int l15 = lane & 15, quad = lane >> 4;

  // Q fragments (B-operand of swapped QK^T): rows qt*128 + wave*32 + g*16 + l15
  const u16* Qr0 = Q + (size_t)(b * NN + qt * 128 + wave * 32 + l15) * SQK + h * DH;
  const u16* Qr1 = Qr0 + (size_t)16 * SQK;
  const bf16x8 aq00 = *(const bf16x8*)(Qr0 + quad * 8);
  const bf16x8 aq01 = *(const bf16x8*)(Qr0 + 32 + quad * 8);
  const bf16x8 aq10 = *(const bf16x8*)(Qr1 + quad * 8);
  const bf16x8 aq11 = *(const bf16x8*)(Qr1 + 32 + quad * 8);

  // staging: LDS slot i -> (row r, physical chunk c); source chunk c^(r&7)
  // (XOR swizzle folded into the GLOBAL gather, LDS writes lane-linear).
  // K rows sigma-permuted: LDS key-row j holds token sigma(j) =
  // bit-permute [b5][b4][b3b2][b1b0] -> [b5][b3b2][b4][b1b0].
  const int i0 = tid, i1 = tid + 256;
  const int r0 = i0 >> 3, s0c = (i0 & 7) ^ (r0 & 7);
  const int r1 = i1 >> 3, s1c = (i1 & 7) ^ (r1 & 7);
  const int kr0 = (r0 & 35) | ((r0 & 12) << 1) | ((r0 & 16) >> 2);  // sigma(r0)
  const int kr1 = (r1 & 35) | ((r1 & 12) << 1) | ((r1 & 16) >> 2);  // sigma(r1)
  const u16* Kp0 = K + (size_t)(b * NN + kr0) * SQK + h * DH + s0c * 8;
  const u16* Kp1 = K + (size_t)(b * NN + kr1) * SQK + h * DH + s1c * 8;
  const u16* Vp0 = Vt + (size_t)((b * NH + h) * DH + r0) * NN + s0c * 8;
  const u16* Vp1 = Vt + (size_t)((b * NH + h) * DH + r1) * NN + s1c * 8;
  const uint32_t* Mp = Mx32 +
      (size_t)(((b * 16 + qt) * 4 + wave) * 2) * 16384 + lane * 8;

  // prologue: tile 0 -> buf0; prefetch tile 1 to regs
  u32x4 krg0 = *(const u32x4*)Kp0;
  u32x4 krg1 = *(const u32x4*)Kp1;
  u32x4 vrg0 = *(const u32x4*)Vp0;
  u32x4 vrg1 = *(const u32x4*)Vp1;
  *(u32x4*)(Ks + i0 * 8) = krg0;
  *(u32x4*)(Ks + i1 * 8) = krg1;
  *(u32x4*)(Vs + i0 * 8) = vrg0;
  *(u32x4*)(Vs + i1 * 8) = vrg1;
  krg0 = *(const u32x4*)(Kp0 + (size_t)64 * SQK);
  krg1 = *(const u32x4*)(Kp1 + (size_t)64 * SQK);
  vrg0 = *(const u32x4*)(Vp0 + 64);
  vrg1 = *(const u32x4*)(Vp1 + 64);

  f32x4 oacc0[4], oacc1[4];
#pragma unroll
  for (int d = 0; d < 4; d++) {
    oacc0[d] = (f32x4){0.f, 0.f, 0.f, 0.f};
    oacc1[d] = (f32x4){0.f, 0.f, 0.f, 0.f};
  }
  f32x4 ol0 = (f32x4){0.f, 0.f, 0.f, 0.f};
  f32x4 ol1 = (f32x4){0.f, 0.f, 0.f, 0.f};

  bf16x8 ones;
  {
    union { uint32_t u; __bf16 h2[2]; } c; c.u = 0x3F803F80u;  // 1.0bf16 x2
#pragma unroll
    for (int j = 0; j < 8; j++) ones[j] = c.h2[0];
  }

  __syncthreads();                         // buf0 visible

  // p = exp(s-20) = exp2(fma(s,log2e,-20*log2e)); cvt_pk packs the pair;
  // one v_and applies both 16-bit masks.
#define SOFTPACK(SARR, M0, M1, APU)                                           \
  do {                                                                        \
    _Pragma("unroll")                                                         \
    for (int ks = 0; ks < 2; ks++) {                                          \
      _Pragma("unroll")                                                       \
      for (int p = 0; p < 4; p++) {                                           \
        int nt = ks * 2 + (p >> 1);                                           \
        int rr = (p & 1) * 2;                                                 \
        float p0 = __builtin_amdgcn_exp2f(__builtin_fmaf(                     \
            SARR[nt][rr], 1.4426950408889634f, -28.853900817779268f));        \
        float p1 = __builtin_amdgcn_exp2f(__builtin_fmaf(                     \
            SARR[nt][rr + 1], 1.4426950408889634f, -28.853900817779268f));    \
        uint32_t word;                                                        \
        asm("v_cvt_pk_bf16_f32 %0, %1, %2" : "=v"(word) : "v"(p0), "v"(p1));  \
        word &= (ks == 0 ? M0 : M1)[p];                                       \
        APU[ks].u[p] = word;                                                  \
      }                                                                       \
    }                                                                         \
  } while (0)

  for (int kt = 0; kt < 32; kt++) {
    // write tile kt+1 -> buf[(kt+1)&1] (vmcnt wait: loads issued one full
    // compute phase ago); then prefetch tile kt+2
    const int wb = ((kt + 1) & 1) * 4096;
    *(u32x4*)(Ks + wb + i0 * 8) = krg0;
    *(u32x4*)(Ks + wb + i1 * 8) = krg1;
    *(u32x4*)(Vs + wb + i0 * 8) = vrg0;
    *(u32x4*)(Vs + wb + i1 * 8) = vrg1;
    krg0 = *(const u32x4*)(Kp0 + (size_t)(kt + 2) * 64 * SQK);
    krg1 = *(const u32x4*)(Kp1 + (size_t)(kt + 2) * 64 * SQK);
    vrg0 = *(const u32x4*)(Vp0 + (kt + 2) * 64);
    vrg1 = *(const u32x4*)(Vp1 + (kt + 2) * 64);
    // mask loads for CURRENT tile (L3-resident; consumed after S phase)
    const uint32_t* Mpk = Mp + kt * 512;
    const u32x4 m0a = *(const u32x4*)(Mpk);
    const u32x4 m0b = *(const u32x4*)(Mpk + 4);
    const u32x4 m1a = *(const u32x4*)(Mpk + 16384);
    const u32x4 m1b = *(const u32x4*)(Mpk + 16384 + 4);

    const u16* Kb = Ks + (kt & 1) * 4096;
    const u16* Vb = Vs + (kt & 1) * 4096;

    // S^T tiles: s = mfma(K_frag, Q_frag); each bk read feeds both g-groups.
    f32x4 s0[4], s1[4];
#pragma unroll
    for (int nt = 0; nt < 4; nt++) {
      s0[nt] = (f32x4){0.f, 0.f, 0.f, 0.f};
      s1[nt] = (f32x4){0.f, 0.f, 0.f, 0.f};
    }
    __builtin_amdgcn_s_setprio(1);         // T5: favor MFMA-issuing wave
#pragma unroll
    for (int nt = 0; nt < 4; nt++) {
      int krow = nt * 16 + l15;
      bf16x8 bkl = *(const bf16x8*)(Kb + krow * 64 + ((quad ^ (krow & 7)) * 8));
      s0[nt] = mfma16(bkl, aq00, s0[nt]);
      s1[nt] = mfma16(bkl, aq10, s1[nt]);
    }
#pragma unroll
    for (int nt = 0; nt < 4; nt++) {
      int krow = nt * 16 + l15;
      bf16x8 bkh = *(const bf16x8*)(Kb + krow * 64 + (((4 + quad) ^ (krow & 7)) * 8));
      s0[nt] = mfma16(bkh, aq01, s0[nt]);
      s1[nt] = mfma16(bkh, aq11, s1[nt]);
    }
    __builtin_amdgcn_s_setprio(0);

    // softmax + bf16 pack + mask, all in registers
    union U { uint32_t u[4]; bf16x8 v; };
    U ap0[2], ap1[2];
    SOFTPACK(s0, m0a, m0b, ap0);
    SOFTPACK(s1, m1a, m1b, ap1);

    // O += P @ V ; l += P @ 1 ; each bv read feeds both g-groups
    __builtin_amdgcn_s_setprio(1);         // T5
#pragma unroll
    for (int ks = 0; ks < 2; ks++) {
      ol0 = mfma16(ap0[ks].v, ones, ol0);
      ol1 = mfma16(ap1[ks].v, ones, ol1);
#pragma unroll
      for (int d = 0; d < 4; d++) {
        int vrow = d * 16 + l15;
        bf16x8 bv = *(const bf16x8*)(Vb + vrow * 64 + (((ks * 4 + quad) ^ (vrow & 7)) * 8));
        oacc0[d] = mfma16(ap0[ks].v, bv, oacc0[d]);
        oacc1[d] = mfma16(ap1[ks].v, bv, oacc1[d]);
      }
    }
    __builtin_amdgcn_s_setprio(0);
    __syncthreads();   // all waves wrote buf[(kt+1)&1] and finished buf[kt&1]
  }
#undef SOFTPACK

  // D rows = quad*4+r within each 16-row group; g=1 is +16 rows
  u16* Og = O + (size_t)(b * NN + qt * 128 + wave * 32 + quad * 4) * QD + h * DH;
#pragma unroll
  for (int r = 0; r < 4; r++) {
    float inv0 = 1.0f / ol0[r];
    float inv1 = 1.0f / ol1[r];
#pragma unroll
    for (int d = 0; d < 4; d++) {
      Og[(size_t)r * QD + d * 16 + l15] = f2bf(oacc0[d][r] * inv0);
      Og[(size_t)(16 + r) * QD + d * 16 + l15] = f2bf(oacc1[d][r] * inv1);
    }
  }
}

extern "C" void kernel_launch(void* const* d_in, const int* in_sizes, int n_in,
                              void* d_out, int out_size, void* d_ws, size_t ws_size,
                              hipStream_t stream) {
  const float* x  = (const float*)d_in[0];
  const int*   mk = (const int*)d_in[1];
  const float* Wq = (const float*)d_in[2];
  const float* Wk = (const float*)d_in[3];
  const float* Wv = (const float*)d_in[4];
  const float* Wo = (const float*)d_in[5];
  const float* bo = (const float*)d_in[6];
  float* out = (float*)d_out;

  char* ws = (char*)d_ws;
  u16* Xb   = (u16*)(ws);                                  // 16 MB
  u16* QKVb = (u16*)(ws + 16777216);                       // 48 MB [8192][3072]
  u16* Vt   = (u16*)(ws + 16777216 + 50331648);            // 16 MB
  u16* Ob   = Xb;  // alias: Xb dead after gemm1; attn writes Ob after gemm1
  char* wx  =  ws + 16777216 + 50331648 + 16777216;        // @80 MB
  u16* Wqkvt = (u16*)(wx);                                 // 6 MB [3072][1024]
  u16* Wot   = (u16*)(wx + 6291456);                       // 2 MB
  uint32_t* Mx32 = (uint32_t*)(wx + 6291456 + 2097152);    // 32 MB @88 MB
  // total ws use: 16+48+16+6+2+32 = 120 MB

  prep_k<<<13312, 256, 0, stream>>>(x, Xb, Wq, Wk, Wv, Wo,
      Wqkvt, Wqkvt + 1024 * QD, Wqkvt + 2048 * QD, Wot, mk, Mx32);

  // fused QKV projection: [8192][1024] x [1024][3072] -> [8192][3072], Q cols scaled 1/8
  gemm_bt_k<0><<<dim3(SQK / 128, MTOK / 128), 256, 0, stream>>>(
      Xb, Wqkvt, QKVb, nullptr, 0.125f, 1024, MTOK, SQK, QD);

  vtrans_k<<<BB * NH * (NN / 64), 256, 0, stream>>>(QKVb + 2048, Vt);
  attn_k<<<BB * NH * (NN / 128), 256, 0, stream>>>(QKVb, QKVb + 1024, Vt, Mx32, Ob);

  gemm_bt_k<1><<<dim3(QD / 128, MTOK / 128), 256, 0, stream>>>(
      Ob, Wot, out, bo, 1.0f, 0, MTOK, QD, QD);
}